// Round 8
// baseline (609.183 us; speedup 1.0000x reference)
//
#include <hip/hip_runtime.h>

// B=4, P=8192, M=2048, K=32, C=64, IN=67(->96 pad), H=128, OC=128, Q=64
// Rows N = 262144. MFMA 16x16x32 bf16. BN1 stats analytic. MLP blocks = 128 rows.

typedef __attribute__((ext_vector_type(8))) short s16x8;
typedef __attribute__((ext_vector_type(4))) float f32x4;

__device__ __forceinline__ unsigned short f2bf(float f) {
  unsigned int u = __float_as_uint(f);
  unsigned int r = u + 0x7fffu + ((u >> 16) & 1u);  // RNE
  return (unsigned short)(r >> 16);
}
__device__ __forceinline__ float bf2f(unsigned short s) {
  return __uint_as_float(((unsigned int)s) << 16);
}

// ------ prep2: weight pack + xyzq (blocks 0..281) | feats transpose (blocks 282..793) ------
__global__ __launch_bounds__(256) void prep2_kernel(const float* __restrict__ W1,
                                                    const float* __restrict__ W2,
                                                    const float* __restrict__ Wq1,
                                                    const float* __restrict__ xyz,
                                                    const float* __restrict__ feats,
                                                    unsigned short* __restrict__ W1p,
                                                    unsigned short* __restrict__ W2p,
                                                    unsigned short* __restrict__ Wq1p,
                                                    float4* __restrict__ xyzq,
                                                    unsigned short* __restrict__ featsT) {
  __shared__ float tile[64][65];
  const int t = threadIdx.x;
  if (blockIdx.x >= 282) {
    const int bx = blockIdx.x - 282;  // 512 tr blocks
    const int b = bx >> 7;
    const int p0 = (bx & 127) * 64;
    {
      const int pp = t & 63, c4 = t >> 6;
#pragma unroll
      for (int j = 0; j < 16; ++j) {
        int c = j * 4 + c4;
        tile[c][pp] = feats[((size_t)(b * 64 + c)) * 8192 + p0 + pp];
      }
    }
    __syncthreads();
    {
      const int cc = t & 63, p4 = t >> 6;
#pragma unroll
      for (int j = 0; j < 16; ++j) {
        int pr = j * 4 + p4;
        featsT[((size_t)(b * 8192 + p0 + pr)) * 64 + cc] = f2bf(tile[cc][pr]);
      }
    }
    return;
  }
  int i = blockIdx.x * 256 + t;
  if (i < 13312) {  // W1p[128][104]: k<64 feats (W1[o][3+k]), k 64..66 xyz, else 0
    int o = i / 104, k = i % 104;
    float v = 0.f;
    if (k < 64) v = W1[o * 67 + 3 + k];
    else if (k < 67) v = W1[o * 67 + (k - 64)];
    W1p[i] = f2bf(v);
    return;
  }
  i -= 13312;
  if (i < 17408) {  // W2p[128][136]
    int o = i / 136, k = i % 136;
    W2p[i] = (k < 128) ? f2bf(W2[o * 128 + k]) : (unsigned short)0;
    return;
  }
  i -= 17408;
  if (i < 8704) {  // Wq1p[64][136]
    int o = i / 136, k = i % 136;
    Wq1p[i] = (k < 128) ? f2bf(Wq1[o * 128 + k]) : (unsigned short)0;
    return;
  }
  i -= 8704;
  if (i < 32768) {
    const float* q = xyz + (size_t)i * 3;
    float x = q[0], y = q[1], z = q[2];
    float4 v; v.x = x; v.y = y; v.z = z; v.w = (x * x + y * y) + z * z;
    xyzq[i] = v;
  }
}

// ---------------- selection (unchanged: paired centers) ----------------
#define CANDMAX 512
__global__ __launch_bounds__(512, 2) void sel3_kernel(const float4* __restrict__ xyzq,
    float* __restrict__ centers_out, int* __restrict__ idx_out) {
  const int t = threadIdx.x, lane = t & 63, wid = t >> 6;
  const int b = blockIdx.y;
  const int m0 = blockIdx.x * 16;  // grid.x = 128
  __shared__ unsigned int hist[2][4096];
  __shared__ unsigned long long cand[2][CANDMAX];
  __shared__ float4 cc4[16];
  __shared__ int selb[2][32];
  __shared__ int ctrl[2][2];
  __shared__ int cutb[2];
  __shared__ int wsum[2][4];

  const float4* xb = xyzq + (size_t)b * 8192;
  float4 pt[16];
#pragma unroll
  for (int i = 0; i < 16; ++i) pt[i] = xb[i * 512 + t];

  if (t < 16) {
    int mIdx = m0 + t;
    int pc = (mIdx * 8191) / 2047;  // floor(linspace(0,P-1,M))
    float4 c = xb[pc];
    cc4[t] = c;
    float* co = centers_out + ((size_t)(b * 2048 + mIdx)) * 3;
    co[0] = c.x; co[1] = c.y; co[2] = c.z;
  }
  for (int j = t; j < 8192; j += 512) ((unsigned int*)hist)[j] = 0;
  if (t < 4) ctrl[t >> 1][t & 1] = 0;
  __syncthreads();

  for (int ci = 0; ci < 8; ++ci) {
    const float4 cA = cc4[2 * ci], cB = cc4[2 * ci + 1];
#pragma unroll
    for (int i = 0; i < 16; ++i) {
      float dotA = (cA.x * pt[i].x + cA.y * pt[i].y) + cA.z * pt[i].z;
      float d2A = (cA.w + pt[i].w) - 2.0f * dotA;
      unsigned int uA = __float_as_uint(d2A);
      uA = (uA & 0x80000000u) ? ~uA : (uA | 0x80000000u);
      atomicAdd(&hist[0][uA >> 20], 1u);
      float dotB = (cB.x * pt[i].x + cB.y * pt[i].y) + cB.z * pt[i].z;
      float d2B = (cB.w + pt[i].w) - 2.0f * dotB;
      unsigned int uB = __float_as_uint(d2B);
      uB = (uB & 0x80000000u) ? ~uB : (uB | 0x80000000u);
      atomicAdd(&hist[1][uB >> 20], 1u);
    }
    __syncthreads();  // B1
    {
      const int h = t >> 8;
      const int th = t & 255;
      const int wl = wid & 3;
      const int base = th * 16;
      const unsigned int* H = hist[h];
      int csum = 0;
#pragma unroll
      for (int j = 0; j < 16; ++j) csum += (int)H[base + j];
      int incl = csum;
#pragma unroll
      for (int d = 1; d < 64; d <<= 1) {
        int v = __shfl_up(incl, d);
        if (lane >= d) incl += v;
      }
      if (lane == 63) wsum[h][wl] = incl;
      __syncthreads();  // B2
      int woff = 0;
      for (int i2 = 0; i2 < wl; ++i2) woff += wsum[h][i2];
      int excl = woff + incl - csum;
      if (excl < 32 && excl + csum >= 32) {
        int cum = excl, binsel = base + 15;
        for (int j = 0; j < 16; ++j) {
          int cv = (int)H[base + j];
          if (cum + cv >= 32) { binsel = base + j; break; }
          cum += cv;
        }
        cutb[h] = binsel;
      }
    }
    __syncthreads();  // B3
    const unsigned int cutA = (unsigned int)cutb[0];
    const unsigned int cutB = (unsigned int)cutb[1];
#pragma unroll
    for (int i = 0; i < 16; ++i) {
      const int pidx = i * 512 + t;
      float dotA = (cA.x * pt[i].x + cA.y * pt[i].y) + cA.z * pt[i].z;
      float d2A = (cA.w + pt[i].w) - 2.0f * dotA;
      unsigned int uA = __float_as_uint(d2A);
      uA = (uA & 0x80000000u) ? ~uA : (uA | 0x80000000u);
      unsigned int keyA = uA >> 20;
      if (keyA < cutA) {
        int pos = atomicAdd(&ctrl[0][0], 1);
        selb[0][pos] = pidx;
      } else if (keyA == cutA) {
        int pos = atomicAdd(&ctrl[0][1], 1);
        if (pos < CANDMAX) cand[0][pos] = ((unsigned long long)uA << 32) | (unsigned int)pidx;
      }
      float dotB = (cB.x * pt[i].x + cB.y * pt[i].y) + cB.z * pt[i].z;
      float d2B = (cB.w + pt[i].w) - 2.0f * dotB;
      unsigned int uB = __float_as_uint(d2B);
      uB = (uB & 0x80000000u) ? ~uB : (uB | 0x80000000u);
      unsigned int keyB = uB >> 20;
      if (keyB < cutB) {
        int pos = atomicAdd(&ctrl[1][0], 1);
        selb[1][pos] = pidx;
      } else if (keyB == cutB) {
        int pos = atomicAdd(&ctrl[1][1], 1);
        if (pos < CANDMAX) cand[1][pos] = ((unsigned long long)uB << 32) | (unsigned int)pidx;
      }
    }
    __syncthreads();  // B4
    if (wid < 2) {
      const int nsel = ctrl[wid][0];
      const int need = 32 - nsel;
      const int nc = min(ctrl[wid][1], CANDMAX);
      volatile unsigned long long* vc = cand[wid];
      for (int r = 0; r < need; ++r) {
        unsigned long long best = ~0ull;
        int bs = -1;
#pragma unroll
        for (int bb = 0; bb < CANDMAX; bb += 64) {
          int j = bb + lane;
          if (j < nc) {
            unsigned long long v = vc[j];
            if (v < best) { best = v; bs = j; }
          }
        }
#pragma unroll
        for (int d = 32; d; d >>= 1) {
          unsigned long long ob = __shfl_xor(best, d);
          int os = __shfl_xor(bs, d);
          if (ob < best) { best = ob; bs = os; }
        }
        if (lane == 0) {
          selb[wid][nsel + r] = (int)(best & 0xffffffffu);
          cand[wid][bs] = ~0ull;
        }
      }
    } else {
      for (int j = t - 128; j < 8192; j += 384) ((unsigned int*)hist)[j] = 0;
    }
    __syncthreads();  // B5
    if (t < 64) {
      int cc = t >> 5;
      idx_out[(size_t)(b * 2048 + m0 + 2 * ci + cc) * 32 + (t & 31)] = selb[cc][t & 31];
    }
    if (t < 4) ctrl[t >> 1][t & 1] = 0;
    __syncthreads();  // B6
  }
}

// ------- cnt: 64 blocks, exclusive 512-point ranges, LDS accumulate + plain-store flush -------
__global__ __launch_bounds__(1024) void cnt_kernel(const float4* __restrict__ xyzq,
    const float* __restrict__ centers, const int* __restrict__ idxb,
    float* __restrict__ cnt, float* __restrict__ scx, float* __restrict__ scy,
    float* __restrict__ scz, float* __restrict__ dstats) {
  const int t = threadIdx.x;
  const int b = blockIdx.x >> 4, ri = blockIdx.x & 15;
  const int pbase = ri * 512;
  __shared__ float L[4][512];
  for (int j = t; j < 2048; j += 1024) ((float*)L)[j] = 0.f;
  __syncthreads();
  float m9[9] = {0.f, 0.f, 0.f, 0.f, 0.f, 0.f, 0.f, 0.f, 0.f};
  for (int i = 0; i < 64; ++i) {
    int e = i * 1024 + t;  // (g,k) flat index within batch
    int p = idxb[b * 65536 + e];
    if ((unsigned)(p - pbase) < 512u) {
      int g = e >> 5;
      const float* cp = centers + ((size_t)(b * 2048 + g)) * 3;
      float cx = cp[0], cy = cp[1], cz = cp[2];
      float4 v = xyzq[(size_t)b * 8192 + p];
      int l = p - pbase;
      atomicAdd(&L[0][l], 1.f);
      atomicAdd(&L[1][l], cx);
      atomicAdd(&L[2][l], cy);
      atomicAdd(&L[3][l], cz);
      float dx = v.x - cx, dy = v.y - cy, dz = v.z - cz;
      m9[0] += dx; m9[1] += dy; m9[2] += dz;
      m9[3] += dx * dx; m9[4] += dy * dy; m9[5] += dz * dz;
      m9[6] += dx * dy; m9[7] += dx * dz; m9[8] += dy * dz;
    }
  }
#pragma unroll
  for (int k = 0; k < 9; ++k) {
#pragma unroll
    for (int d = 1; d < 64; d <<= 1) m9[k] += __shfl_xor(m9[k], d);
  }
  if ((t & 63) == 0) {
#pragma unroll
    for (int k = 0; k < 9; ++k) atomicAdd(&dstats[k], m9[k]);
  }
  __syncthreads();
  if (t < 512) {
    int gp = b * 8192 + pbase + t;
    cnt[gp] = L[0][t];
    scx[gp] = L[1][t];
    scy[gp] = L[2][t];
    scz[gp] = L[3][t];
  }
}

// ---------------- weighted Gram for analytic BN1 stats (unchanged) ----------------
__global__ __launch_bounds__(256) void gram_kernel(const float* __restrict__ feats,
    const float4* __restrict__ xyzq, const float* __restrict__ cnt,
    const float* __restrict__ scx, const float* __restrict__ scy,
    const float* __restrict__ scz, float* __restrict__ Sff,
    float* __restrict__ Sfd, float* __restrict__ Fbar) {
  const int t = threadIdx.x;
  const int b = blockIdx.y;
  __shared__ float fT[128][68];
  __shared__ float cw_s[128], e_s[3][128];
  const int c1 = (t >> 4) * 4, c2 = (t & 15) * 4;
  const int aux = t & 3;
  const bool doaux = ((t & 15) < 4);
  float acc[4][4] = {};
  float accA[4] = {};
  for (int chunk = 0; chunk < 4; ++chunk) {
    const int p0 = blockIdx.x * 512 + chunk * 128;
    __syncthreads();
#pragma unroll
    for (int j = 0; j < 32; ++j) {
      int idx = j * 256 + t;
      int cch = idx >> 7, pp = idx & 127;
      fT[pp][cch] = feats[((size_t)(b * 64 + cch)) * 8192 + p0 + pp];
    }
    if (t < 128) {
      int gp = b * 8192 + p0 + t;
      float cw = cnt[gp];
      cw_s[t] = cw;
      float4 v = xyzq[gp];
      e_s[0][t] = cw * v.x - scx[gp];
      e_s[1][t] = cw * v.y - scy[gp];
      e_s[2][t] = cw * v.z - scz[gp];
    }
    __syncthreads();
    for (int pp = 0; pp < 128; ++pp) {
      float cw = cw_s[pp];
      float4 f1 = *(const float4*)&fT[pp][c1];
      float4 f2 = *(const float4*)&fT[pp][c2];
      float f1a[4] = {f1.x, f1.y, f1.z, f1.w};
      float f2a[4] = {f2.x, f2.y, f2.z, f2.w};
#pragma unroll
      for (int i = 0; i < 4; ++i) {
        float wsc = f1a[i] * cw;
#pragma unroll
        for (int j = 0; j < 4; ++j) acc[i][j] += wsc * f2a[j];
      }
      if (doaux) {
        float mult = (aux < 3) ? e_s[aux][pp] : cw;
#pragma unroll
        for (int i = 0; i < 4; ++i) accA[i] += f1a[i] * mult;
      }
    }
  }
#pragma unroll
  for (int i = 0; i < 4; ++i)
#pragma unroll
    for (int j = 0; j < 4; ++j) atomicAdd(&Sff[(c1 + i) * 64 + c2 + j], acc[i][j]);
  if (doaux) {
#pragma unroll
    for (int i = 0; i < 4; ++i) {
      if (aux < 3) atomicAdd(&Sfd[(c1 + i) * 3 + aux], accA[i]);
      else atomicAdd(&Fbar[c1 + i], accA[i]);
    }
  }
}

// ---------------- finalize analytic BN1 stats (unchanged) ----------------
__global__ __launch_bounds__(256) void fin_kernel(const float* __restrict__ W1,
    const float* __restrict__ b1, const float* __restrict__ Sff,
    const float* __restrict__ Sfd, const float* __restrict__ Fbar,
    const float* __restrict__ dstats, float* __restrict__ stats) {
  __shared__ float sS[4096], sFd[192], sFb[64], sD[16];
  const int t = threadIdx.x;
  for (int j = t; j < 4096; j += 256) sS[j] = Sff[j];
  if (t < 192) sFd[t] = Sfd[t];
  if (t < 64) sFb[t] = Fbar[t];
  if (t < 9) sD[t] = dstats[t];
  __syncthreads();
  const int c = t >> 1, h = t & 1;
  float wf[64];
#pragma unroll
  for (int i = 0; i < 64; ++i) wf[i] = W1[c * 67 + 3 + i];
  const float wx0 = W1[c * 67], wx1 = W1[c * 67 + 1], wx2 = W1[c * 67 + 2];
  float qacc = 0.f;
  for (int i = h * 32; i < h * 32 + 32; ++i) {
    float rd = 0.f;
    const float4* row = (const float4*)&sS[i * 64];
#pragma unroll
    for (int j4 = 0; j4 < 16; ++j4) {
      float4 v = row[j4];
      rd += v.x * wf[j4 * 4] + v.y * wf[j4 * 4 + 1] + v.z * wf[j4 * 4 + 2] + v.w * wf[j4 * 4 + 3];
    }
    rd += 2.f * (sFd[i * 3] * wx0 + sFd[i * 3 + 1] * wx1 + sFd[i * 3 + 2] * wx2);
    qacc += wf[i] * rd;
  }
  qacc += __shfl_xor(qacc, 1);
  if (h == 0) {
    const float N = 262144.f;
    float lin = 0.f;
#pragma unroll
    for (int i = 0; i < 64; ++i) lin += wf[i] * sFb[i];
    lin += wx0 * sD[0] + wx1 * sD[1] + wx2 * sD[2];
    float bb = b1[c];
    float Sy = lin + bb * N;
    float dd = wx0 * wx0 * sD[3] + wx1 * wx1 * sD[4] + wx2 * wx2 * sD[5]
             + 2.f * (wx0 * wx1 * sD[6] + wx0 * wx2 * sD[7] + wx1 * wx2 * sD[8]);
    float Sy2 = qacc + dd + 2.f * bb * lin + bb * bb * N;
    stats[c] = Sy;
    stats[128 + c] = Sy2;
  }
}

// ====== 128-row MFMA MLP: wave rw owns rows rw*16..+15, all 128 cols ======
// LDS: W1l 26624 (-> Wq1 / sred overlay) | W2l half 17408 (-> epilogue overlay) | A2 34816
// STAGE 2 = BN2-stats pass; STAGE 3 = final epilogue (recompute path).
template <int STAGE>
__global__ __launch_bounds__(512, 2) void mlp_kernel(
    const float* __restrict__ xyz, const unsigned short* __restrict__ featsT,
    const int* __restrict__ idxbuf, const float* __restrict__ centers,
    const unsigned short* __restrict__ W1p_g, const float* __restrict__ b1,
    const float* __restrict__ g1, const float* __restrict__ be1,
    const unsigned short* __restrict__ W2p_g, const float* __restrict__ b2,
    const float* __restrict__ g2, const float* __restrict__ be2,
    const unsigned short* __restrict__ Wq1p_g, const float* __restrict__ bq1,
    const float* __restrict__ Wq2, const float* __restrict__ bq2,
    float* __restrict__ stats, float* __restrict__ out_agg) {
  const int t = threadIdx.x;
  const int T = blockIdx.x;      // grid 2048
  const int G0 = T * 4;          // 4 groups / block
  const int b = G0 >> 11;

  __shared__ __align__(16) unsigned short W1l[13312];  // 26624 B
  __shared__ __align__(16) unsigned short W2l[8704];   // 17408 B
  __shared__ __align__(16) unsigned short A2l[17408];  // 34816 B
  __shared__ float sc1a[128], sh1a[128], sc2a[128], sh2a[128];
  float* sredS = (float*)W1l;          // stage2 overlay (dead after G1)
  float* sredQ = (float*)W1l + 1024;
  float* sv  = (float*)W2l;            // stage3 epilogue overlay (dead after G2h1)
  float* wv  = (float*)W2l + 128;
  float* agg = (float*)W2l + 256;      // 1024 floats

  const int lane = t & 63, rw = t >> 6;    // 8 row-waves
  const int m = lane & 15, q = lane >> 4;

  for (int i = t; i < 1664; i += 512) ((s16x8*)W1l)[i] = ((const s16x8*)W1p_g)[i];
  for (int i = t; i < 1088; i += 512) ((s16x8*)W2l)[i] = ((const s16x8*)W2p_g)[i];

  const float invN = 1.0f / 262144.0f;
  if (t < 128) {
    float mu = stats[t] * invN;
    float var = stats[128 + t] * invN - mu * mu;
    float s = g1[t] * rsqrtf(var + 1e-5f);
    sc1a[t] = s;
    sh1a[t] = (b1[t] - mu) * s + be1[t];
    if (STAGE == 3) {
      float mu2 = stats[256 + t] * invN;
      float var2 = stats[384 + t] * invN - mu2 * mu2;
      float s2 = g2[t] * rsqrtf(var2 + 1e-5f);
      sc2a[t] = s2;
      sh2a[t] = (b2[t] - mu2) * s2 + be2[t];
    }
  }

  // gather: row r = rw*16+m; lanes q cover k-chunks
  const int r = rw * 16 + m;
  const int g = G0 + (r >> 5);
  const int p = idxbuf[(size_t)g * 32 + (r & 31)];
  const unsigned short* fr = featsT + ((size_t)(b * 8192) + p) * 64;
  s16x8 a0 = *(const s16x8*)(fr + q * 8);
  s16x8 a1 = *(const s16x8*)(fr + 32 + q * 8);
  s16x8 a2 = (s16x8){0, 0, 0, 0, 0, 0, 0, 0};
  if (q == 0) {
    const float* cp = centers + (size_t)g * 3;
    const float* qp = xyz + ((size_t)(b * 8192) + p) * 3;
    a2[0] = (short)f2bf(qp[0] - cp[0]);
    a2[1] = (short)f2bf(qp[1] - cp[1]);
    a2[2] = (short)f2bf(qp[2] - cp[2]);
  }
  __syncthreads();  // b0

  // ---- G1: 96 -> 128 (wave: 16 rows x 128 cols) ----
  {
    f32x4 acc[8];
#pragma unroll
    for (int nt = 0; nt < 8; ++nt) acc[nt] = (f32x4){0.f, 0.f, 0.f, 0.f};
#pragma unroll
    for (int kb = 0; kb < 3; ++kb) {
      s16x8 a = (kb == 0) ? a0 : ((kb == 1) ? a1 : a2);
#pragma unroll
      for (int nt = 0; nt < 8; ++nt) {
        s16x8 bf = *(const s16x8*)(W1l + (nt * 16 + m) * 104 + kb * 32 + q * 8);
        acc[nt] = __builtin_amdgcn_mfma_f32_16x16x32_bf16(a, bf, acc[nt], 0, 0, 0);
      }
    }
#pragma unroll
    for (int nt = 0; nt < 8; ++nt) {
      int ch = nt * 16 + m;
      float s = sc1a[ch], o = sh1a[ch];
#pragma unroll
      for (int r4 = 0; r4 < 4; ++r4)
        A2l[(rw * 16 + q * 4 + r4) * 136 + ch] = f2bf(fmaxf(acc[nt][r4] * s + o, 0.f));
    }
  }
  __syncthreads();  // b1: A2 ready; W1l dead

  // ---- G2: 128 -> 128 in two 64-col halves (wave: 16 rows x 64 cols/half) ----
  float fl[2][4][4];
  const int aoff2 = (rw * 16 + m) * 136 + q * 8;
  for (int h2 = 0; h2 < 2; ++h2) {
    if (h2 == 1) {
      __syncthreads();  // b2: G2h0's W2l reads done (stage2: also sred flush phase)
      for (int i = t; i < 1088; i += 512) ((s16x8*)W2l)[i] = ((const s16x8*)W2p_g)[1088 + i];
      if (STAGE == 3) {
        for (int i = t; i < 1088; i += 512) ((s16x8*)W1l)[i] = ((const s16x8*)Wq1p_g)[i];
      }
      __syncthreads();  // b3
    }
    f32x4 bacc[4];
#pragma unroll
    for (int nt = 0; nt < 4; ++nt) bacc[nt] = (f32x4){0.f, 0.f, 0.f, 0.f};
#pragma unroll
    for (int kb = 0; kb < 4; ++kb) {
      s16x8 a = *(const s16x8*)(A2l + aoff2 + kb * 32);
#pragma unroll
      for (int nt = 0; nt < 4; ++nt) {
        s16x8 bf = *(const s16x8*)(W2l + (nt * 16 + m) * 136 + kb * 32 + q * 8);
        bacc[nt] = __builtin_amdgcn_mfma_f32_16x16x32_bf16(a, bf, bacc[nt], 0, 0, 0);
      }
    }
    if (STAGE == 2) {
#pragma unroll
      for (int nt = 0; nt < 4; ++nt) {
        int ch = h2 * 64 + nt * 16 + m;
        float bb = b2[ch];
        float s = 0.f, sq = 0.f;
#pragma unroll
        for (int r4 = 0; r4 < 4; ++r4) {
          float y = bacc[nt][r4] + bb;
          s += y; sq += y * y;
        }
        s += __shfl_xor(s, 16); sq += __shfl_xor(sq, 16);
        s += __shfl_xor(s, 32); sq += __shfl_xor(sq, 32);
        if (q == 0) { sredS[ch * 8 + rw] = s; sredQ[ch * 8 + rw] = sq; }
      }
      __syncthreads();
      if (t < 64) {
        int ch = h2 * 64 + t;
        float ss = 0.f, qq = 0.f;
#pragma unroll
        for (int i2 = 0; i2 < 8; ++i2) { ss += sredS[ch * 8 + i2]; qq += sredQ[ch * 8 + i2]; }
        atomicAdd(&stats[256 + ch], ss);
        atomicAdd(&stats[384 + ch], qq);
      }
      if (h2 == 1) return;
    } else {
#pragma unroll
      for (int nt = 0; nt < 4; ++nt) {
        int ch = h2 * 64 + nt * 16 + m;
        float s = sc2a[ch], o = sh2a[ch];
#pragma unroll
        for (int r4 = 0; r4 < 4; ++r4)
          fl[h2][nt][r4] = fmaxf(bacc[nt][r4] * s + o, 0.f);
      }
    }
  }

  __syncthreads();  // b4: all A2/W2l reads done
  // A3 (FL bf16) -> A2 region
#pragma unroll
  for (int h2 = 0; h2 < 2; ++h2)
#pragma unroll
    for (int nt = 0; nt < 4; ++nt) {
      int ch = h2 * 64 + nt * 16 + m;
#pragma unroll
      for (int r4 = 0; r4 < 4; ++r4)
        A2l[(rw * 16 + q * 4 + r4) * 136 + ch] = f2bf(fl[h2][nt][r4]);
    }
  __syncthreads();  // b5: A3 + Wq1 ready

  // ---- Q: 128 -> 64 per wave (cols 0..63), score reduce ----
  {
    f32x4 qacc[4];
#pragma unroll
    for (int nt = 0; nt < 4; ++nt) qacc[nt] = (f32x4){0.f, 0.f, 0.f, 0.f};
#pragma unroll
    for (int kb = 0; kb < 4; ++kb) {
      s16x8 a = *(const s16x8*)(A2l + aoff2 + kb * 32);
#pragma unroll
      for (int nt = 0; nt < 4; ++nt) {
        s16x8 bf = *(const s16x8*)(W1l + (nt * 16 + m) * 136 + kb * 32 + q * 8);
        qacc[nt] = __builtin_amdgcn_mfma_f32_16x16x32_bf16(a, bf, qacc[nt], 0, 0, 0);
      }
    }
    float ba[4], w[4];
#pragma unroll
    for (int nt = 0; nt < 4; ++nt) { ba[nt] = bq1[nt * 16 + m]; w[nt] = Wq2[nt * 16 + m]; }
    float part[4];
#pragma unroll
    for (int r4 = 0; r4 < 4; ++r4) {
      float pv = 0.f;
#pragma unroll
      for (int nt = 0; nt < 4; ++nt) pv += fmaxf(qacc[nt][r4] + ba[nt], 0.f) * w[nt];
      part[r4] = pv;
    }
#pragma unroll
    for (int d = 1; d < 16; d <<= 1) {
#pragma unroll
      for (int r4 = 0; r4 < 4; ++r4) part[r4] += __shfl_xor(part[r4], d);
    }
    if (m == 0) {
#pragma unroll
      for (int r4 = 0; r4 < 4; ++r4) sv[rw * 16 + q * 4 + r4] = part[r4];
    }
  }
  __syncthreads();  // b6
  if (t < 128) {
    float x = sv[t] + bq2[0];
    float mx = x;
#pragma unroll
    for (int d = 16; d; d >>= 1) mx = fmaxf(mx, __shfl_xor(mx, d, 32));
    float e = expf(x - mx);
    float ssum = e;
#pragma unroll
    for (int d = 16; d; d >>= 1) ssum += __shfl_xor(ssum, d, 32);
    wv[t] = e / ssum;
  }
  __syncthreads();  // b7
  {
    float wreg[4];
#pragma unroll
    for (int r4 = 0; r4 < 4; ++r4) wreg[r4] = wv[rw * 16 + q * 4 + r4];
    const int gl = rw >> 1, par = rw & 1;
#pragma unroll
    for (int h2 = 0; h2 < 2; ++h2)
#pragma unroll
      for (int nt = 0; nt < 4; ++nt) {
        float pv = 0.f;
#pragma unroll
        for (int r4 = 0; r4 < 4; ++r4) pv += wreg[r4] * fl[h2][nt][r4];
        pv += __shfl_xor(pv, 16);
        pv += __shfl_xor(pv, 32);
        if (q == 0) {
          int ch = h2 * 64 + nt * 16 + m;
          agg[(gl * 128 + ch) * 2 + par] = pv;
        }
      }
  }
  __syncthreads();  // b8
  {
    int gl = t >> 7, ch = t & 127;
    float v = agg[(gl * 128 + ch) * 2] + agg[(gl * 128 + ch) * 2 + 1];
    out_agg[((size_t)(b * 128 + ch)) * 2048 + ((G0 + gl) & 2047)] = v;
  }
}

// ====== fwd (Y2 path): 128-row; G1+BN1+G2 -> BN2 stats + Y2 (bf16, pre-bias) ======
__global__ __launch_bounds__(512, 2) void fwd_kernel(
    const float* __restrict__ xyz, const unsigned short* __restrict__ featsT,
    const int* __restrict__ idxbuf, const float* __restrict__ centers,
    const unsigned short* __restrict__ W1p_g, const float* __restrict__ b1,
    const float* __restrict__ g1, const float* __restrict__ be1,
    const unsigned short* __restrict__ W2p_g, const float* __restrict__ b2,
    float* __restrict__ stats, unsigned short* __restrict__ Y2) {
  const int t = threadIdx.x;
  const int T = blockIdx.x;   // grid 2048
  const int G0 = T * 4;
  const int b = G0 >> 11;

  __shared__ __align__(16) unsigned short W1l[13312];
  __shared__ __align__(16) unsigned short W2l[8704];
  __shared__ __align__(16) unsigned short A2l[17408];
  __shared__ float sc1a[128], sh1a[128];
  float* sredS = (float*)W1l;
  float* sredQ = (float*)W1l + 1024;

  const int lane = t & 63, rw = t >> 6;
  const int m = lane & 15, q = lane >> 4;

  for (int i = t; i < 1664; i += 512) ((s16x8*)W1l)[i] = ((const s16x8*)W1p_g)[i];
  for (int i = t; i < 1088; i += 512) ((s16x8*)W2l)[i] = ((const s16x8*)W2p_g)[i];

  const float invN = 1.0f / 262144.0f;
  if (t < 128) {
    float mu = stats[t] * invN;
    float var = stats[128 + t] * invN - mu * mu;
    float s = g1[t] * rsqrtf(var + 1e-5f);
    sc1a[t] = s;
    sh1a[t] = (b1[t] - mu) * s + be1[t];
  }
  const int r = rw * 16 + m;
  const int g = G0 + (r >> 5);
  const int p = idxbuf[(size_t)g * 32 + (r & 31)];
  const unsigned short* fr = featsT + ((size_t)(b * 8192) + p) * 64;
  s16x8 a0 = *(const s16x8*)(fr + q * 8);
  s16x8 a1 = *(const s16x8*)(fr + 32 + q * 8);
  s16x8 a2 = (s16x8){0, 0, 0, 0, 0, 0, 0, 0};
  if (q == 0) {
    const float* cp = centers + (size_t)g * 3;
    const float* qp = xyz + ((size_t)(b * 8192) + p) * 3;
    a2[0] = (short)f2bf(qp[0] - cp[0]);
    a2[1] = (short)f2bf(qp[1] - cp[1]);
    a2[2] = (short)f2bf(qp[2] - cp[2]);
  }
  __syncthreads();  // b0

  {
    f32x4 acc[8];
#pragma unroll
    for (int nt = 0; nt < 8; ++nt) acc[nt] = (f32x4){0.f, 0.f, 0.f, 0.f};
#pragma unroll
    for (int kb = 0; kb < 3; ++kb) {
      s16x8 a = (kb == 0) ? a0 : ((kb == 1) ? a1 : a2);
#pragma unroll
      for (int nt = 0; nt < 8; ++nt) {
        s16x8 bf = *(const s16x8*)(W1l + (nt * 16 + m) * 104 + kb * 32 + q * 8);
        acc[nt] = __builtin_amdgcn_mfma_f32_16x16x32_bf16(a, bf, acc[nt], 0, 0, 0);
      }
    }
#pragma unroll
    for (int nt = 0; nt < 8; ++nt) {
      int ch = nt * 16 + m;
      float s = sc1a[ch], o = sh1a[ch];
#pragma unroll
      for (int r4 = 0; r4 < 4; ++r4)
        A2l[(rw * 16 + q * 4 + r4) * 136 + ch] = f2bf(fmaxf(acc[nt][r4] * s + o, 0.f));
    }
  }
  __syncthreads();  // b1

  float y2r[2][4][4];
  const int aoff2 = (rw * 16 + m) * 136 + q * 8;
  for (int h2 = 0; h2 < 2; ++h2) {
    if (h2 == 1) {
      __syncthreads();
      for (int i = t; i < 1088; i += 512) ((s16x8*)W2l)[i] = ((const s16x8*)W2p_g)[1088 + i];
      __syncthreads();
    }
    f32x4 bacc[4];
#pragma unroll
    for (int nt = 0; nt < 4; ++nt) bacc[nt] = (f32x4){0.f, 0.f, 0.f, 0.f};
#pragma unroll
    for (int kb = 0; kb < 4; ++kb) {
      s16x8 a = *(const s16x8*)(A2l + aoff2 + kb * 32);
#pragma unroll
      for (int nt = 0; nt < 4; ++nt) {
        s16x8 bf = *(const s16x8*)(W2l + (nt * 16 + m) * 136 + kb * 32 + q * 8);
        bacc[nt] = __builtin_amdgcn_mfma_f32_16x16x32_bf16(a, bf, bacc[nt], 0, 0, 0);
      }
    }
#pragma unroll
    for (int nt = 0; nt < 4; ++nt) {
      int ch = h2 * 64 + nt * 16 + m;
      float bb = b2[ch];
      float s = 0.f, sq = 0.f;
#pragma unroll
      for (int r4 = 0; r4 < 4; ++r4) {
        float y = bacc[nt][r4] + bb;
        s += y; sq += y * y;
        y2r[h2][nt][r4] = bacc[nt][r4];
      }
      s += __shfl_xor(s, 16); sq += __shfl_xor(sq, 16);
      s += __shfl_xor(s, 32); sq += __shfl_xor(sq, 32);
      if (q == 0) { sredS[ch * 8 + rw] = s; sredQ[ch * 8 + rw] = sq; }
    }
    __syncthreads();
    if (t < 64) {
      int ch = h2 * 64 + t;
      float ss = 0.f, qq = 0.f;
#pragma unroll
      for (int i2 = 0; i2 < 8; ++i2) { ss += sredS[ch * 8 + i2]; qq += sredQ[ch * 8 + i2]; }
      atomicAdd(&stats[256 + ch], ss);
      atomicAdd(&stats[384 + ch], qq);
    }
  }
  __syncthreads();  // A2 reads done
#pragma unroll
  for (int h2 = 0; h2 < 2; ++h2)
#pragma unroll
    for (int nt = 0; nt < 4; ++nt) {
      int ch = h2 * 64 + nt * 16 + m;
#pragma unroll
      for (int r4 = 0; r4 < 4; ++r4)
        A2l[(rw * 16 + q * 4 + r4) * 136 + ch] = f2bf(y2r[h2][nt][r4]);
    }
  __syncthreads();
  for (int i = t; i < 2048; i += 512) {
    int row = i >> 4, off = (i & 15) * 8;
    *(s16x8*)(Y2 + ((size_t)(T * 128 + row)) * 128 + off) = *(const s16x8*)(A2l + row * 136 + off);
  }
}

// ---------------- fin2: stream Y2, BN2+ReLU, Q-score, softmax, aggregate (64-row) ----------------
__global__ __launch_bounds__(512) void fin2_kernel(
    const unsigned short* __restrict__ Y2, const float* __restrict__ stats,
    const float* __restrict__ g2, const float* __restrict__ be2,
    const float* __restrict__ b2, const unsigned short* __restrict__ Wq1p_g,
    const float* __restrict__ bq1, const float* __restrict__ Wq2,
    const float* __restrict__ bq2, float* __restrict__ out_agg) {
  const int t = threadIdx.x;
  const int T = blockIdx.x;   // grid 4096, 64 rows each
  const int G0 = T * 2;
  const int b = G0 >> 11;

  __shared__ __align__(16) unsigned short Wq1l[8704];
  __shared__ float sc2a[128], sh2a[128];
  __shared__ float sv2[128], wv[64], agg2[512];

  const int lane = t & 63, wid = t >> 6;
  const int m = lane & 15, q = lane >> 4;
  const int rw = wid & 3, cw = wid >> 2;

  for (int i = t; i < 1088; i += 512) ((s16x8*)Wq1l)[i] = ((const s16x8*)Wq1p_g)[i];
  const float invN = 1.0f / 262144.0f;
  if (t < 128) {
    float mu2 = stats[256 + t] * invN;
    float var2 = stats[384 + t] * invN - mu2 * mu2;
    float s2 = g2[t] * rsqrtf(var2 + 1e-5f);
    sc2a[t] = s2;
    sh2a[t] = (b2[t] - mu2) * s2 + be2[t];
  }
  const int row = rw * 16 + m;
  const unsigned short* yr = Y2 + ((size_t)(T * 64 + row)) * 128;
  s16x8 yv[4];
#pragma unroll
  for (int kb = 0; kb < 4; ++kb) yv[kb] = *(const s16x8*)(yr + kb * 32 + q * 8);
  __syncthreads();  // b0

  float flr[4][8];
  s16x8 af[4];
#pragma unroll
  for (int kb = 0; kb < 4; ++kb) {
#pragma unroll
    for (int j = 0; j < 8; ++j) {
      int ch = kb * 32 + q * 8 + j;
      float f = fmaxf(bf2f((unsigned short)yv[kb][j]) * sc2a[ch] + sh2a[ch], 0.f);
      flr[kb][j] = f;
      af[kb][j] = (short)f2bf(f);
    }
  }
  {
    f32x4 qacc[2];
#pragma unroll
    for (int nt = 0; nt < 2; ++nt) qacc[nt] = (f32x4){0.f, 0.f, 0.f, 0.f};
#pragma unroll
    for (int kb = 0; kb < 4; ++kb) {
#pragma unroll
      for (int nt = 0; nt < 2; ++nt) {
        s16x8 bf = *(const s16x8*)(Wq1l + (cw * 32 + nt * 16 + m) * 136 + kb * 32 + q * 8);
        qacc[nt] = __builtin_amdgcn_mfma_f32_16x16x32_bf16(af[kb], bf, qacc[nt], 0, 0, 0);
      }
    }
    int qc0 = cw * 32 + m, qc1 = qc0 + 16;
    float ba0 = bq1[qc0], ba1 = bq1[qc1];
    float w0 = Wq2[qc0], w1 = Wq2[qc1];
    float part[4];
#pragma unroll
    for (int r4 = 0; r4 < 4; ++r4) {
      float v0 = fmaxf(qacc[0][r4] + ba0, 0.f);
      float v1 = fmaxf(qacc[1][r4] + ba1, 0.f);
      part[r4] = v0 * w0 + v1 * w1;
    }
#pragma unroll
    for (int d = 1; d < 16; d <<= 1) {
#pragma unroll
      for (int r4 = 0; r4 < 4; ++r4) part[r4] += __shfl_xor(part[r4], d);
    }
    if (m == 0) {
#pragma unroll
      for (int r4 = 0; r4 < 4; ++r4) sv2[(rw * 16 + q * 4 + r4) * 2 + cw] = part[r4];
    }
  }
  __syncthreads();  // b1
  if (t < 64) {
    float x = sv2[t * 2] + sv2[t * 2 + 1] + bq2[0];
    float mx = x;
#pragma unroll
    for (int d = 16; d; d >>= 1) mx = fmaxf(mx, __shfl_xor(mx, d, 32));
    float e = expf(x - mx);
    float ssum = e;
#pragma unroll
    for (int d = 16; d; d >>= 1) ssum += __shfl_xor(ssum, d, 32);
    wv[t] = e / ssum;
  }
  __syncthreads();  // b2
  if (cw == 0) {
    const float w = wv[row];
    const int gl = rw >> 1, rwpar = rw & 1;
#pragma unroll
    for (int kb = 0; kb < 4; ++kb) {
#pragma unroll
      for (int j = 0; j < 8; ++j) {
        float pv = w * flr[kb][j];
        pv += __shfl_xor(pv, 1);
        pv += __shfl_xor(pv, 2);
        pv += __shfl_xor(pv, 4);
        pv += __shfl_xor(pv, 8);
        if (m == 0) agg2[(gl * 128 + kb * 32 + q * 8 + j) * 2 + rwpar] = pv;
      }
    }
  }
  __syncthreads();  // b3
  if (t < 256) {
    int gl = t >> 7, ch = t & 127;
    float v = agg2[(gl * 128 + ch) * 2] + agg2[(gl * 128 + ch) * 2 + 1];
    out_agg[((size_t)(b * 128 + ch)) * 2048 + ((G0 + gl) & 2047)] = v;
  }
}

extern "C" void kernel_launch(void* const* d_in, const int* in_sizes, int n_in,
                              void* d_out, int out_size, void* d_ws, size_t ws_size,
                              hipStream_t stream) {
  const float* xyz   = (const float*)d_in[0];
  const float* feats = (const float*)d_in[1];
  const float* W1    = (const float*)d_in[2];
  const float* b1    = (const float*)d_in[3];
  const float* g1    = (const float*)d_in[4];
  const float* be1   = (const float*)d_in[5];
  const float* W2    = (const float*)d_in[6];
  const float* b2    = (const float*)d_in[7];
  const float* g2    = (const float*)d_in[8];
  const float* be2   = (const float*)d_in[9];
  const float* Wq1   = (const float*)d_in[10];
  const float* bq1   = (const float*)d_in[11];
  const float* Wq2   = (const float*)d_in[12];
  const float* bq2   = (const float*)d_in[13];

  float* outp    = (float*)d_out;
  float* centers = outp;           // (4,2048,3)
  float* out_agg = outp + 24576;   // (4,128,2048)

  // ws layout: 6.4 MB base + optional Y2 (64 MB) at +8 MB
  char* base = (char*)d_ws;
  unsigned short* featsT = (unsigned short*)base;                  // 4,194,304
  float4* xyzq  = (float4*)(base + 4194304);                       //   524,288
  int*    idxb  = (int*)(base + 4718592);                          // 1,048,576
  unsigned short* W1p  = (unsigned short*)(base + 5767168);        //    26,624
  unsigned short* W2p  = (unsigned short*)(base + 5793792);        //    34,816
  unsigned short* Wq1p = (unsigned short*)(base + 5828608);        //    17,408
  float* stats  = (float*)(base + 5846016);   // zero region start (4880 floats)
  float* dstats = stats + 512;
  float* Fbar   = stats + 528;
  float* Sfd    = stats + 592;
  float* Sff    = stats + 784;
  float* cntp   = stats + 4880;               // fully overwritten by cnt_kernel
  float* scx    = cntp + 32768;
  float* scy    = scx + 32768;
  float* scz    = scy + 32768;
  unsigned short* Y2 = (unsigned short*)(base + 8388608);  // 67,108,864 B
  const bool bigws = ws_size >= (size_t)75497472;

  hipMemsetAsync(stats, 0, 19520, stream);
  prep2_kernel<<<794, 256, 0, stream>>>(W1, W2, Wq1, xyz, feats, W1p, W2p, Wq1p, xyzq, featsT);
  sel3_kernel<<<dim3(128, 4), 512, 0, stream>>>(xyzq, centers, idxb);
  cnt_kernel<<<64, 1024, 0, stream>>>(xyzq, centers, idxb, cntp, scx, scy, scz, dstats);
  gram_kernel<<<dim3(16, 4), 256, 0, stream>>>(feats, xyzq, cntp, scx, scy, scz, Sff, Sfd, Fbar);
  fin_kernel<<<1, 256, 0, stream>>>(W1, b1, Sff, Sfd, Fbar, dstats, stats);
  if (bigws) {
    fwd_kernel<<<2048, 512, 0, stream>>>(xyz, featsT, idxb, centers,
                                         W1p, b1, g1, be1, W2p, b2, stats, Y2);
    fin2_kernel<<<4096, 512, 0, stream>>>(Y2, stats, g2, be2, b2,
                                          Wq1p, bq1, Wq2, bq2, out_agg);
  } else {
    mlp_kernel<2><<<2048, 512, 0, stream>>>(xyz, featsT, idxb, centers,
                                            W1p, b1, g1, be1, W2p, b2, g2, be2,
                                            Wq1p, bq1, Wq2, bq2, stats, out_agg);
    mlp_kernel<3><<<2048, 512, 0, stream>>>(xyz, featsT, idxb, centers,
                                            W1p, b1, g1, be1, W2p, b2, g2, be2,
                                            Wq1p, bq1, Wq2, bq2, stats, out_agg);
  }
}

// Round 9
// 443.169 us; speedup vs baseline: 1.3746x; 1.3746x over previous
//
#include <hip/hip_runtime.h>

// B=4, P=8192, M=2048, K=32, C=64, IN=67(->96 pad), H=128, OC=128, Q=64
// Rows N = 262144. MFMA 16x16x32 bf16. BN1 stats analytic. MLP blocks = 128 rows.

typedef __attribute__((ext_vector_type(8))) short s16x8;
typedef __attribute__((ext_vector_type(4))) float f32x4;

__device__ __forceinline__ unsigned short f2bf(float f) {
  unsigned int u = __float_as_uint(f);
  unsigned int r = u + 0x7fffu + ((u >> 16) & 1u);  // RNE
  return (unsigned short)(r >> 16);
}
__device__ __forceinline__ float bf2f(unsigned short s) {
  return __uint_as_float(((unsigned int)s) << 16);
}

// ------ prep2: weight pack + xyzq (blocks 0..281) | feats transpose (blocks 282..793) ------
__global__ __launch_bounds__(256) void prep2_kernel(const float* __restrict__ W1,
                                                    const float* __restrict__ W2,
                                                    const float* __restrict__ Wq1,
                                                    const float* __restrict__ xyz,
                                                    const float* __restrict__ feats,
                                                    unsigned short* __restrict__ W1p,
                                                    unsigned short* __restrict__ W2p,
                                                    unsigned short* __restrict__ Wq1p,
                                                    float4* __restrict__ xyzq,
                                                    unsigned short* __restrict__ featsT) {
  __shared__ float tile[64][65];
  const int t = threadIdx.x;
  if (blockIdx.x >= 282) {
    const int bx = blockIdx.x - 282;  // 512 tr blocks
    const int b = bx >> 7;
    const int p0 = (bx & 127) * 64;
    {
      const int pp = t & 63, c4 = t >> 6;
#pragma unroll
      for (int j = 0; j < 16; ++j) {
        int c = j * 4 + c4;
        tile[c][pp] = feats[((size_t)(b * 64 + c)) * 8192 + p0 + pp];
      }
    }
    __syncthreads();
    {
      const int cc = t & 63, p4 = t >> 6;
#pragma unroll
      for (int j = 0; j < 16; ++j) {
        int pr = j * 4 + p4;
        featsT[((size_t)(b * 8192 + p0 + pr)) * 64 + cc] = f2bf(tile[cc][pr]);
      }
    }
    return;
  }
  int i = blockIdx.x * 256 + t;
  if (i < 13312) {  // W1p[128][104]: k<64 feats (W1[o][3+k]), k 64..66 xyz, else 0
    int o = i / 104, k = i % 104;
    float v = 0.f;
    if (k < 64) v = W1[o * 67 + 3 + k];
    else if (k < 67) v = W1[o * 67 + (k - 64)];
    W1p[i] = f2bf(v);
    return;
  }
  i -= 13312;
  if (i < 17408) {  // W2p[128][136]
    int o = i / 136, k = i % 136;
    W2p[i] = (k < 128) ? f2bf(W2[o * 128 + k]) : (unsigned short)0;
    return;
  }
  i -= 17408;
  if (i < 8704) {  // Wq1p[64][136]
    int o = i / 136, k = i % 136;
    Wq1p[i] = (k < 128) ? f2bf(Wq1[o * 128 + k]) : (unsigned short)0;
    return;
  }
  i -= 8704;
  if (i < 32768) {
    const float* q = xyz + (size_t)i * 3;
    float x = q[0], y = q[1], z = q[2];
    float4 v; v.x = x; v.y = y; v.z = z; v.w = (x * x + y * y) + z * z;
    xyzq[i] = v;
  }
}

// ---------------- selection (unchanged: paired centers) ----------------
#define CANDMAX 512
__global__ __launch_bounds__(512, 2) void sel3_kernel(const float4* __restrict__ xyzq,
    float* __restrict__ centers_out, int* __restrict__ idx_out) {
  const int t = threadIdx.x, lane = t & 63, wid = t >> 6;
  const int b = blockIdx.y;
  const int m0 = blockIdx.x * 16;  // grid.x = 128
  __shared__ unsigned int hist[2][4096];
  __shared__ unsigned long long cand[2][CANDMAX];
  __shared__ float4 cc4[16];
  __shared__ int selb[2][32];
  __shared__ int ctrl[2][2];
  __shared__ int cutb[2];
  __shared__ int wsum[2][4];

  const float4* xb = xyzq + (size_t)b * 8192;
  float4 pt[16];
#pragma unroll
  for (int i = 0; i < 16; ++i) pt[i] = xb[i * 512 + t];

  if (t < 16) {
    int mIdx = m0 + t;
    int pc = (mIdx * 8191) / 2047;  // floor(linspace(0,P-1,M))
    float4 c = xb[pc];
    cc4[t] = c;
    float* co = centers_out + ((size_t)(b * 2048 + mIdx)) * 3;
    co[0] = c.x; co[1] = c.y; co[2] = c.z;
  }
  for (int j = t; j < 8192; j += 512) ((unsigned int*)hist)[j] = 0;
  if (t < 4) ctrl[t >> 1][t & 1] = 0;
  __syncthreads();

  for (int ci = 0; ci < 8; ++ci) {
    const float4 cA = cc4[2 * ci], cB = cc4[2 * ci + 1];
#pragma unroll
    for (int i = 0; i < 16; ++i) {
      float dotA = (cA.x * pt[i].x + cA.y * pt[i].y) + cA.z * pt[i].z;
      float d2A = (cA.w + pt[i].w) - 2.0f * dotA;
      unsigned int uA = __float_as_uint(d2A);
      uA = (uA & 0x80000000u) ? ~uA : (uA | 0x80000000u);
      atomicAdd(&hist[0][uA >> 20], 1u);
      float dotB = (cB.x * pt[i].x + cB.y * pt[i].y) + cB.z * pt[i].z;
      float d2B = (cB.w + pt[i].w) - 2.0f * dotB;
      unsigned int uB = __float_as_uint(d2B);
      uB = (uB & 0x80000000u) ? ~uB : (uB | 0x80000000u);
      atomicAdd(&hist[1][uB >> 20], 1u);
    }
    __syncthreads();  // B1
    {
      const int h = t >> 8;
      const int th = t & 255;
      const int wl = wid & 3;
      const int base = th * 16;
      const unsigned int* H = hist[h];
      int csum = 0;
#pragma unroll
      for (int j = 0; j < 16; ++j) csum += (int)H[base + j];
      int incl = csum;
#pragma unroll
      for (int d = 1; d < 64; d <<= 1) {
        int v = __shfl_up(incl, d);
        if (lane >= d) incl += v;
      }
      if (lane == 63) wsum[h][wl] = incl;
      __syncthreads();  // B2
      int woff = 0;
      for (int i2 = 0; i2 < wl; ++i2) woff += wsum[h][i2];
      int excl = woff + incl - csum;
      if (excl < 32 && excl + csum >= 32) {
        int cum = excl, binsel = base + 15;
        for (int j = 0; j < 16; ++j) {
          int cv = (int)H[base + j];
          if (cum + cv >= 32) { binsel = base + j; break; }
          cum += cv;
        }
        cutb[h] = binsel;
      }
    }
    __syncthreads();  // B3
    const unsigned int cutA = (unsigned int)cutb[0];
    const unsigned int cutB = (unsigned int)cutb[1];
#pragma unroll
    for (int i = 0; i < 16; ++i) {
      const int pidx = i * 512 + t;
      float dotA = (cA.x * pt[i].x + cA.y * pt[i].y) + cA.z * pt[i].z;
      float d2A = (cA.w + pt[i].w) - 2.0f * dotA;
      unsigned int uA = __float_as_uint(d2A);
      uA = (uA & 0x80000000u) ? ~uA : (uA | 0x80000000u);
      unsigned int keyA = uA >> 20;
      if (keyA < cutA) {
        int pos = atomicAdd(&ctrl[0][0], 1);
        selb[0][pos] = pidx;
      } else if (keyA == cutA) {
        int pos = atomicAdd(&ctrl[0][1], 1);
        if (pos < CANDMAX) cand[0][pos] = ((unsigned long long)uA << 32) | (unsigned int)pidx;
      }
      float dotB = (cB.x * pt[i].x + cB.y * pt[i].y) + cB.z * pt[i].z;
      float d2B = (cB.w + pt[i].w) - 2.0f * dotB;
      unsigned int uB = __float_as_uint(d2B);
      uB = (uB & 0x80000000u) ? ~uB : (uB | 0x80000000u);
      unsigned int keyB = uB >> 20;
      if (keyB < cutB) {
        int pos = atomicAdd(&ctrl[1][0], 1);
        selb[1][pos] = pidx;
      } else if (keyB == cutB) {
        int pos = atomicAdd(&ctrl[1][1], 1);
        if (pos < CANDMAX) cand[1][pos] = ((unsigned long long)uB << 32) | (unsigned int)pidx;
      }
    }
    __syncthreads();  // B4
    if (wid < 2) {
      const int nsel = ctrl[wid][0];
      const int need = 32 - nsel;
      const int nc = min(ctrl[wid][1], CANDMAX);
      volatile unsigned long long* vc = cand[wid];
      for (int r = 0; r < need; ++r) {
        unsigned long long best = ~0ull;
        int bs = -1;
#pragma unroll
        for (int bb = 0; bb < CANDMAX; bb += 64) {
          int j = bb + lane;
          if (j < nc) {
            unsigned long long v = vc[j];
            if (v < best) { best = v; bs = j; }
          }
        }
#pragma unroll
        for (int d = 32; d; d >>= 1) {
          unsigned long long ob = __shfl_xor(best, d);
          int os = __shfl_xor(bs, d);
          if (ob < best) { best = ob; bs = os; }
        }
        if (lane == 0) {
          selb[wid][nsel + r] = (int)(best & 0xffffffffu);
          cand[wid][bs] = ~0ull;
        }
      }
    } else {
      for (int j = t - 128; j < 8192; j += 384) ((unsigned int*)hist)[j] = 0;
    }
    __syncthreads();  // B5
    if (t < 64) {
      int cc = t >> 5;
      idx_out[(size_t)(b * 2048 + m0 + 2 * ci + cc) * 32 + (t & 31)] = selb[cc][t & 31];
    }
    if (t < 4) ctrl[t >> 1][t & 1] = 0;
    __syncthreads();  // B6
  }
}

// ------- cntA: 256 blocks (4b x 4quar x 16 eslice), 4 iterations, LDS partial + plain store -------
__global__ __launch_bounds__(1024) void cntA_kernel(const float4* __restrict__ xyzq,
    const float* __restrict__ centers, const int* __restrict__ idxb,
    float* __restrict__ partials, float* __restrict__ dstats) {
  const int t = threadIdx.x;
  const int b = blockIdx.x >> 6, quar = (blockIdx.x >> 4) & 3, esl = blockIdx.x & 15;
  const int pbase = quar * 2048;
  __shared__ float L[4][2048];
  __shared__ float mred[16][9];
  for (int j = t; j < 8192; j += 1024) ((float*)L)[j] = 0.f;
  __syncthreads();
  float m9[9] = {0.f, 0.f, 0.f, 0.f, 0.f, 0.f, 0.f, 0.f, 0.f};
#pragma unroll
  for (int i = 0; i < 4; ++i) {
    int e = esl * 4096 + i * 1024 + t;  // (g,k) flat index within batch
    int p = idxb[b * 65536 + e];
    if ((unsigned)(p - pbase) < 2048u) {
      int g = e >> 5;
      const float* cp = centers + ((size_t)(b * 2048 + g)) * 3;
      float cx = cp[0], cy = cp[1], cz = cp[2];
      float4 v = xyzq[(size_t)b * 8192 + p];
      int l = p - pbase;
      atomicAdd(&L[0][l], 1.f);
      atomicAdd(&L[1][l], cx);
      atomicAdd(&L[2][l], cy);
      atomicAdd(&L[3][l], cz);
      float dx = v.x - cx, dy = v.y - cy, dz = v.z - cz;
      m9[0] += dx; m9[1] += dy; m9[2] += dz;
      m9[3] += dx * dx; m9[4] += dy * dy; m9[5] += dz * dz;
      m9[6] += dx * dy; m9[7] += dx * dz; m9[8] += dy * dz;
    }
  }
#pragma unroll
  for (int k = 0; k < 9; ++k) {
#pragma unroll
    for (int d = 1; d < 64; d <<= 1) m9[k] += __shfl_xor(m9[k], d);
  }
  if ((t & 63) == 0) {
#pragma unroll
    for (int k = 0; k < 9; ++k) mred[t >> 6][k] = m9[k];
  }
  __syncthreads();
  if (t < 9) {
    float s = 0.f;
#pragma unroll
    for (int w = 0; w < 16; ++w) s += mred[w][t];
    atomicAdd(&dstats[t], s);
  }
  float* pb = partials + (size_t)blockIdx.x * 8192;
  for (int j = t; j < 8192; j += 1024) pb[j] = ((float*)L)[j];
}

// ------- cntB: reduce 16 entry-slice partials -> cnt/scx/scy/scz -------
__global__ __launch_bounds__(256) void cntB_kernel(const float* __restrict__ partials,
    float* __restrict__ cnt, float* __restrict__ scx, float* __restrict__ scy,
    float* __restrict__ scz) {
  const int idx = blockIdx.x * 256 + threadIdx.x;  // 0..131071
  const int pt = idx & 2047;
  const int arr = (idx >> 11) & 3;
  const int quar = (idx >> 13) & 3;
  const int b = idx >> 15;
  const float* base = partials + ((size_t)((b * 4 + quar) * 16)) * 8192 + arr * 2048 + pt;
  float s = 0.f;
#pragma unroll
  for (int e = 0; e < 16; ++e) s += base[(size_t)e * 8192];
  const int gp = b * 8192 + quar * 2048 + pt;
  if (arr == 0) cnt[gp] = s;
  else if (arr == 1) scx[gp] = s;
  else if (arr == 2) scy[gp] = s;
  else scz[gp] = s;
}

// ------- cnt16 fallback (R5 version) when ws < 16 MB -------
__global__ __launch_bounds__(1024) void cnt16_kernel(const float4* __restrict__ xyzq,
    const float* __restrict__ centers, const int* __restrict__ idxb,
    float* __restrict__ cnt, float* __restrict__ scx, float* __restrict__ scy,
    float* __restrict__ scz, float* __restrict__ dstats) {
  const int t = threadIdx.x;
  const int b = blockIdx.x >> 2, quar = blockIdx.x & 3;
  const int pbase = quar * 2048;
  __shared__ float L[4][2048];
  for (int j = t; j < 8192; j += 1024) ((float*)L)[j] = 0.f;
  __syncthreads();
  float m9[9] = {0.f, 0.f, 0.f, 0.f, 0.f, 0.f, 0.f, 0.f, 0.f};
  for (int i = 0; i < 64; ++i) {
    int e = i * 1024 + t;
    int p = idxb[b * 65536 + e];
    if (p >= pbase && p < pbase + 2048) {
      int g = e >> 5;
      const float* cp = centers + ((size_t)(b * 2048 + g)) * 3;
      float cx = cp[0], cy = cp[1], cz = cp[2];
      float4 v = xyzq[(size_t)b * 8192 + p];
      int l = p - pbase;
      atomicAdd(&L[0][l], 1.f);
      atomicAdd(&L[1][l], cx);
      atomicAdd(&L[2][l], cy);
      atomicAdd(&L[3][l], cz);
      float dx = v.x - cx, dy = v.y - cy, dz = v.z - cz;
      m9[0] += dx; m9[1] += dy; m9[2] += dz;
      m9[3] += dx * dx; m9[4] += dy * dy; m9[5] += dz * dz;
      m9[6] += dx * dy; m9[7] += dx * dz; m9[8] += dy * dz;
    }
  }
#pragma unroll
  for (int k = 0; k < 9; ++k) {
#pragma unroll
    for (int d = 1; d < 64; d <<= 1) m9[k] += __shfl_xor(m9[k], d);
  }
  if ((t & 63) == 0) {
#pragma unroll
    for (int k = 0; k < 9; ++k) atomicAdd(&dstats[k], m9[k]);
  }
  __syncthreads();
  for (int j = t; j < 2048; j += 1024) {
    int gp = b * 8192 + pbase + j;
    cnt[gp] = L[0][j];
    scx[gp] = L[1][j];
    scy[gp] = L[2][j];
    scz[gp] = L[3][j];
  }
}

// ---------------- weighted Gram for analytic BN1 stats; grid (64,4) ----------------
__global__ __launch_bounds__(256) void gram_kernel(const float* __restrict__ feats,
    const float4* __restrict__ xyzq, const float* __restrict__ cnt,
    const float* __restrict__ scx, const float* __restrict__ scy,
    const float* __restrict__ scz, float* __restrict__ Sff,
    float* __restrict__ Sfd, float* __restrict__ Fbar) {
  const int t = threadIdx.x;
  const int b = blockIdx.y;
  const int p0 = blockIdx.x * 128;
  __shared__ float fT[128][68];
  __shared__ float cw_s[128], e_s[3][128];
  const int c1 = (t >> 4) * 4, c2 = (t & 15) * 4;
  const int aux = t & 3;
  const bool doaux = ((t & 15) < 4);
  float acc[4][4] = {};
  float accA[4] = {};
#pragma unroll
  for (int j = 0; j < 32; ++j) {
    int idx = j * 256 + t;
    int cch = idx >> 7, pp = idx & 127;
    fT[pp][cch] = feats[((size_t)(b * 64 + cch)) * 8192 + p0 + pp];
  }
  if (t < 128) {
    int gp = b * 8192 + p0 + t;
    float cw = cnt[gp];
    cw_s[t] = cw;
    float4 v = xyzq[gp];
    e_s[0][t] = cw * v.x - scx[gp];
    e_s[1][t] = cw * v.y - scy[gp];
    e_s[2][t] = cw * v.z - scz[gp];
  }
  __syncthreads();
  for (int pp = 0; pp < 128; ++pp) {
    float cw = cw_s[pp];
    float4 f1 = *(const float4*)&fT[pp][c1];
    float4 f2 = *(const float4*)&fT[pp][c2];
    float f1a[4] = {f1.x, f1.y, f1.z, f1.w};
    float f2a[4] = {f2.x, f2.y, f2.z, f2.w};
#pragma unroll
    for (int i = 0; i < 4; ++i) {
      float wsc = f1a[i] * cw;
#pragma unroll
      for (int j = 0; j < 4; ++j) acc[i][j] += wsc * f2a[j];
    }
    if (doaux) {
      float mult = (aux < 3) ? e_s[aux][pp] : cw;
#pragma unroll
      for (int i = 0; i < 4; ++i) accA[i] += f1a[i] * mult;
    }
  }
#pragma unroll
  for (int i = 0; i < 4; ++i)
#pragma unroll
    for (int j = 0; j < 4; ++j) atomicAdd(&Sff[(c1 + i) * 64 + c2 + j], acc[i][j]);
  if (doaux) {
#pragma unroll
    for (int i = 0; i < 4; ++i) {
      if (aux < 3) atomicAdd(&Sfd[(c1 + i) * 3 + aux], accA[i]);
      else atomicAdd(&Fbar[c1 + i], accA[i]);
    }
  }
}

// ---------------- finalize analytic BN1 stats (unchanged) ----------------
__global__ __launch_bounds__(256) void fin_kernel(const float* __restrict__ W1,
    const float* __restrict__ b1, const float* __restrict__ Sff,
    const float* __restrict__ Sfd, const float* __restrict__ Fbar,
    const float* __restrict__ dstats, float* __restrict__ stats) {
  __shared__ float sS[4096], sFd[192], sFb[64], sD[16];
  const int t = threadIdx.x;
  for (int j = t; j < 4096; j += 256) sS[j] = Sff[j];
  if (t < 192) sFd[t] = Sfd[t];
  if (t < 64) sFb[t] = Fbar[t];
  if (t < 9) sD[t] = dstats[t];
  __syncthreads();
  const int c = t >> 1, h = t & 1;
  float wf[64];
#pragma unroll
  for (int i = 0; i < 64; ++i) wf[i] = W1[c * 67 + 3 + i];
  const float wx0 = W1[c * 67], wx1 = W1[c * 67 + 1], wx2 = W1[c * 67 + 2];
  float qacc = 0.f;
  for (int i = h * 32; i < h * 32 + 32; ++i) {
    float rd = 0.f;
    const float4* row = (const float4*)&sS[i * 64];
#pragma unroll
    for (int j4 = 0; j4 < 16; ++j4) {
      float4 v = row[j4];
      rd += v.x * wf[j4 * 4] + v.y * wf[j4 * 4 + 1] + v.z * wf[j4 * 4 + 2] + v.w * wf[j4 * 4 + 3];
    }
    rd += 2.f * (sFd[i * 3] * wx0 + sFd[i * 3 + 1] * wx1 + sFd[i * 3 + 2] * wx2);
    qacc += wf[i] * rd;
  }
  qacc += __shfl_xor(qacc, 1);
  if (h == 0) {
    const float N = 262144.f;
    float lin = 0.f;
#pragma unroll
    for (int i = 0; i < 64; ++i) lin += wf[i] * sFb[i];
    lin += wx0 * sD[0] + wx1 * sD[1] + wx2 * sD[2];
    float bb = b1[c];
    float Sy = lin + bb * N;
    float dd = wx0 * wx0 * sD[3] + wx1 * wx1 * sD[4] + wx2 * wx2 * sD[5]
             + 2.f * (wx0 * wx1 * sD[6] + wx0 * wx2 * sD[7] + wx1 * wx2 * sD[8]);
    float Sy2 = qacc + dd + 2.f * bb * lin + bb * bb * N;
    stats[c] = Sy;
    stats[128 + c] = Sy2;
  }
}

// ====== 128-row MFMA MLP (unchanged from R8) ======
template <int STAGE>
__global__ __launch_bounds__(512, 2) void mlp_kernel(
    const float* __restrict__ xyz, const unsigned short* __restrict__ featsT,
    const int* __restrict__ idxbuf, const float* __restrict__ centers,
    const unsigned short* __restrict__ W1p_g, const float* __restrict__ b1,
    const float* __restrict__ g1, const float* __restrict__ be1,
    const unsigned short* __restrict__ W2p_g, const float* __restrict__ b2,
    const float* __restrict__ g2, const float* __restrict__ be2,
    const unsigned short* __restrict__ Wq1p_g, const float* __restrict__ bq1,
    const float* __restrict__ Wq2, const float* __restrict__ bq2,
    float* __restrict__ stats, float* __restrict__ out_agg) {
  const int t = threadIdx.x;
  const int T = blockIdx.x;      // grid 2048
  const int G0 = T * 4;          // 4 groups / block
  const int b = G0 >> 11;

  __shared__ __align__(16) unsigned short W1l[13312];
  __shared__ __align__(16) unsigned short W2l[8704];
  __shared__ __align__(16) unsigned short A2l[17408];
  __shared__ float sc1a[128], sh1a[128], sc2a[128], sh2a[128];
  float* sredS = (float*)W1l;
  float* sredQ = (float*)W1l + 1024;
  float* sv  = (float*)W2l;
  float* wv  = (float*)W2l + 128;
  float* agg = (float*)W2l + 256;

  const int lane = t & 63, rw = t >> 6;
  const int m = lane & 15, q = lane >> 4;

  for (int i = t; i < 1664; i += 512) ((s16x8*)W1l)[i] = ((const s16x8*)W1p_g)[i];
  for (int i = t; i < 1088; i += 512) ((s16x8*)W2l)[i] = ((const s16x8*)W2p_g)[i];

  const float invN = 1.0f / 262144.0f;
  if (t < 128) {
    float mu = stats[t] * invN;
    float var = stats[128 + t] * invN - mu * mu;
    float s = g1[t] * rsqrtf(var + 1e-5f);
    sc1a[t] = s;
    sh1a[t] = (b1[t] - mu) * s + be1[t];
    if (STAGE == 3) {
      float mu2 = stats[256 + t] * invN;
      float var2 = stats[384 + t] * invN - mu2 * mu2;
      float s2 = g2[t] * rsqrtf(var2 + 1e-5f);
      sc2a[t] = s2;
      sh2a[t] = (b2[t] - mu2) * s2 + be2[t];
    }
  }

  const int r = rw * 16 + m;
  const int g = G0 + (r >> 5);
  const int p = idxbuf[(size_t)g * 32 + (r & 31)];
  const unsigned short* fr = featsT + ((size_t)(b * 8192) + p) * 64;
  s16x8 a0 = *(const s16x8*)(fr + q * 8);
  s16x8 a1 = *(const s16x8*)(fr + 32 + q * 8);
  s16x8 a2 = (s16x8){0, 0, 0, 0, 0, 0, 0, 0};
  if (q == 0) {
    const float* cp = centers + (size_t)g * 3;
    const float* qp = xyz + ((size_t)(b * 8192) + p) * 3;
    a2[0] = (short)f2bf(qp[0] - cp[0]);
    a2[1] = (short)f2bf(qp[1] - cp[1]);
    a2[2] = (short)f2bf(qp[2] - cp[2]);
  }
  __syncthreads();  // b0

  {
    f32x4 acc[8];
#pragma unroll
    for (int nt = 0; nt < 8; ++nt) acc[nt] = (f32x4){0.f, 0.f, 0.f, 0.f};
#pragma unroll
    for (int kb = 0; kb < 3; ++kb) {
      s16x8 a = (kb == 0) ? a0 : ((kb == 1) ? a1 : a2);
#pragma unroll
      for (int nt = 0; nt < 8; ++nt) {
        s16x8 bf = *(const s16x8*)(W1l + (nt * 16 + m) * 104 + kb * 32 + q * 8);
        acc[nt] = __builtin_amdgcn_mfma_f32_16x16x32_bf16(a, bf, acc[nt], 0, 0, 0);
      }
    }
#pragma unroll
    for (int nt = 0; nt < 8; ++nt) {
      int ch = nt * 16 + m;
      float s = sc1a[ch], o = sh1a[ch];
#pragma unroll
      for (int r4 = 0; r4 < 4; ++r4)
        A2l[(rw * 16 + q * 4 + r4) * 136 + ch] = f2bf(fmaxf(acc[nt][r4] * s + o, 0.f));
    }
  }
  __syncthreads();  // b1

  float fl[2][4][4];
  const int aoff2 = (rw * 16 + m) * 136 + q * 8;
  for (int h2 = 0; h2 < 2; ++h2) {
    if (h2 == 1) {
      __syncthreads();  // b2
      for (int i = t; i < 1088; i += 512) ((s16x8*)W2l)[i] = ((const s16x8*)W2p_g)[1088 + i];
      if (STAGE == 3) {
        for (int i = t; i < 1088; i += 512) ((s16x8*)W1l)[i] = ((const s16x8*)Wq1p_g)[i];
      }
      __syncthreads();  // b3
    }
    f32x4 bacc[4];
#pragma unroll
    for (int nt = 0; nt < 4; ++nt) bacc[nt] = (f32x4){0.f, 0.f, 0.f, 0.f};
#pragma unroll
    for (int kb = 0; kb < 4; ++kb) {
      s16x8 a = *(const s16x8*)(A2l + aoff2 + kb * 32);
#pragma unroll
      for (int nt = 0; nt < 4; ++nt) {
        s16x8 bf = *(const s16x8*)(W2l + (nt * 16 + m) * 136 + kb * 32 + q * 8);
        bacc[nt] = __builtin_amdgcn_mfma_f32_16x16x32_bf16(a, bf, bacc[nt], 0, 0, 0);
      }
    }
    if (STAGE == 2) {
#pragma unroll
      for (int nt = 0; nt < 4; ++nt) {
        int ch = h2 * 64 + nt * 16 + m;
        float bb = b2[ch];
        float s = 0.f, sq = 0.f;
#pragma unroll
        for (int r4 = 0; r4 < 4; ++r4) {
          float y = bacc[nt][r4] + bb;
          s += y; sq += y * y;
        }
        s += __shfl_xor(s, 16); sq += __shfl_xor(sq, 16);
        s += __shfl_xor(s, 32); sq += __shfl_xor(sq, 32);
        if (q == 0) { sredS[ch * 8 + rw] = s; sredQ[ch * 8 + rw] = sq; }
      }
      __syncthreads();
      if (t < 64) {
        int ch = h2 * 64 + t;
        float ss = 0.f, qq = 0.f;
#pragma unroll
        for (int i2 = 0; i2 < 8; ++i2) { ss += sredS[ch * 8 + i2]; qq += sredQ[ch * 8 + i2]; }
        atomicAdd(&stats[256 + ch], ss);
        atomicAdd(&stats[384 + ch], qq);
      }
      if (h2 == 1) return;
    } else {
#pragma unroll
      for (int nt = 0; nt < 4; ++nt) {
        int ch = h2 * 64 + nt * 16 + m;
        float s = sc2a[ch], o = sh2a[ch];
#pragma unroll
        for (int r4 = 0; r4 < 4; ++r4)
          fl[h2][nt][r4] = fmaxf(bacc[nt][r4] * s + o, 0.f);
      }
    }
  }

  __syncthreads();  // b4
#pragma unroll
  for (int h2 = 0; h2 < 2; ++h2)
#pragma unroll
    for (int nt = 0; nt < 4; ++nt) {
      int ch = h2 * 64 + nt * 16 + m;
#pragma unroll
      for (int r4 = 0; r4 < 4; ++r4)
        A2l[(rw * 16 + q * 4 + r4) * 136 + ch] = f2bf(fl[h2][nt][r4]);
    }
  __syncthreads();  // b5

  {
    f32x4 qacc[4];
#pragma unroll
    for (int nt = 0; nt < 4; ++nt) qacc[nt] = (f32x4){0.f, 0.f, 0.f, 0.f};
#pragma unroll
    for (int kb = 0; kb < 4; ++kb) {
      s16x8 a = *(const s16x8*)(A2l + aoff2 + kb * 32);
#pragma unroll
      for (int nt = 0; nt < 4; ++nt) {
        s16x8 bf = *(const s16x8*)(W1l + (nt * 16 + m) * 136 + kb * 32 + q * 8);
        qacc[nt] = __builtin_amdgcn_mfma_f32_16x16x32_bf16(a, bf, qacc[nt], 0, 0, 0);
      }
    }
    float ba[4], w[4];
#pragma unroll
    for (int nt = 0; nt < 4; ++nt) { ba[nt] = bq1[nt * 16 + m]; w[nt] = Wq2[nt * 16 + m]; }
    float part[4];
#pragma unroll
    for (int r4 = 0; r4 < 4; ++r4) {
      float pv = 0.f;
#pragma unroll
      for (int nt = 0; nt < 4; ++nt) pv += fmaxf(qacc[nt][r4] + ba[nt], 0.f) * w[nt];
      part[r4] = pv;
    }
#pragma unroll
    for (int d = 1; d < 16; d <<= 1) {
#pragma unroll
      for (int r4 = 0; r4 < 4; ++r4) part[r4] += __shfl_xor(part[r4], d);
    }
    if (m == 0) {
#pragma unroll
      for (int r4 = 0; r4 < 4; ++r4) sv[rw * 16 + q * 4 + r4] = part[r4];
    }
  }
  __syncthreads();  // b6
  if (t < 128) {
    float x = sv[t] + bq2[0];
    float mx = x;
#pragma unroll
    for (int d = 16; d; d >>= 1) mx = fmaxf(mx, __shfl_xor(mx, d, 32));
    float e = expf(x - mx);
    float ssum = e;
#pragma unroll
    for (int d = 16; d; d >>= 1) ssum += __shfl_xor(ssum, d, 32);
    wv[t] = e / ssum;
  }
  __syncthreads();  // b7
  {
    float wreg[4];
#pragma unroll
    for (int r4 = 0; r4 < 4; ++r4) wreg[r4] = wv[rw * 16 + q * 4 + r4];
    const int gl = rw >> 1, par = rw & 1;
#pragma unroll
    for (int h2 = 0; h2 < 2; ++h2)
#pragma unroll
      for (int nt = 0; nt < 4; ++nt) {
        float pv = 0.f;
#pragma unroll
        for (int r4 = 0; r4 < 4; ++r4) pv += wreg[r4] * fl[h2][nt][r4];
        pv += __shfl_xor(pv, 16);
        pv += __shfl_xor(pv, 32);
        if (q == 0) {
          int ch = h2 * 64 + nt * 16 + m;
          agg[(gl * 128 + ch) * 2 + par] = pv;
        }
      }
  }
  __syncthreads();  // b8
  {
    int gl = t >> 7, ch = t & 127;
    float v = agg[(gl * 128 + ch) * 2] + agg[(gl * 128 + ch) * 2 + 1];
    out_agg[((size_t)(b * 128 + ch)) * 2048 + ((G0 + gl) & 2047)] = v;
  }
}

// ====== fwd (Y2 path, unchanged from R8) ======
__global__ __launch_bounds__(512, 2) void fwd_kernel(
    const float* __restrict__ xyz, const unsigned short* __restrict__ featsT,
    const int* __restrict__ idxbuf, const float* __restrict__ centers,
    const unsigned short* __restrict__ W1p_g, const float* __restrict__ b1,
    const float* __restrict__ g1, const float* __restrict__ be1,
    const unsigned short* __restrict__ W2p_g, const float* __restrict__ b2,
    float* __restrict__ stats, unsigned short* __restrict__ Y2) {
  const int t = threadIdx.x;
  const int T = blockIdx.x;   // grid 2048
  const int G0 = T * 4;
  const int b = G0 >> 11;

  __shared__ __align__(16) unsigned short W1l[13312];
  __shared__ __align__(16) unsigned short W2l[8704];
  __shared__ __align__(16) unsigned short A2l[17408];
  __shared__ float sc1a[128], sh1a[128];
  float* sredS = (float*)W1l;
  float* sredQ = (float*)W1l + 1024;

  const int lane = t & 63, rw = t >> 6;
  const int m = lane & 15, q = lane >> 4;

  for (int i = t; i < 1664; i += 512) ((s16x8*)W1l)[i] = ((const s16x8*)W1p_g)[i];
  for (int i = t; i < 1088; i += 512) ((s16x8*)W2l)[i] = ((const s16x8*)W2p_g)[i];

  const float invN = 1.0f / 262144.0f;
  if (t < 128) {
    float mu = stats[t] * invN;
    float var = stats[128 + t] * invN - mu * mu;
    float s = g1[t] * rsqrtf(var + 1e-5f);
    sc1a[t] = s;
    sh1a[t] = (b1[t] - mu) * s + be1[t];
  }
  const int r = rw * 16 + m;
  const int g = G0 + (r >> 5);
  const int p = idxbuf[(size_t)g * 32 + (r & 31)];
  const unsigned short* fr = featsT + ((size_t)(b * 8192) + p) * 64;
  s16x8 a0 = *(const s16x8*)(fr + q * 8);
  s16x8 a1 = *(const s16x8*)(fr + 32 + q * 8);
  s16x8 a2 = (s16x8){0, 0, 0, 0, 0, 0, 0, 0};
  if (q == 0) {
    const float* cp = centers + (size_t)g * 3;
    const float* qp = xyz + ((size_t)(b * 8192) + p) * 3;
    a2[0] = (short)f2bf(qp[0] - cp[0]);
    a2[1] = (short)f2bf(qp[1] - cp[1]);
    a2[2] = (short)f2bf(qp[2] - cp[2]);
  }
  __syncthreads();  // b0

  {
    f32x4 acc[8];
#pragma unroll
    for (int nt = 0; nt < 8; ++nt) acc[nt] = (f32x4){0.f, 0.f, 0.f, 0.f};
#pragma unroll
    for (int kb = 0; kb < 3; ++kb) {
      s16x8 a = (kb == 0) ? a0 : ((kb == 1) ? a1 : a2);
#pragma unroll
      for (int nt = 0; nt < 8; ++nt) {
        s16x8 bf = *(const s16x8*)(W1l + (nt * 16 + m) * 104 + kb * 32 + q * 8);
        acc[nt] = __builtin_amdgcn_mfma_f32_16x16x32_bf16(a, bf, acc[nt], 0, 0, 0);
      }
    }
#pragma unroll
    for (int nt = 0; nt < 8; ++nt) {
      int ch = nt * 16 + m;
      float s = sc1a[ch], o = sh1a[ch];
#pragma unroll
      for (int r4 = 0; r4 < 4; ++r4)
        A2l[(rw * 16 + q * 4 + r4) * 136 + ch] = f2bf(fmaxf(acc[nt][r4] * s + o, 0.f));
    }
  }
  __syncthreads();  // b1

  float y2r[2][4][4];
  const int aoff2 = (rw * 16 + m) * 136 + q * 8;
  for (int h2 = 0; h2 < 2; ++h2) {
    if (h2 == 1) {
      __syncthreads();
      for (int i = t; i < 1088; i += 512) ((s16x8*)W2l)[i] = ((const s16x8*)W2p_g)[1088 + i];
      __syncthreads();
    }
    f32x4 bacc[4];
#pragma unroll
    for (int nt = 0; nt < 4; ++nt) bacc[nt] = (f32x4){0.f, 0.f, 0.f, 0.f};
#pragma unroll
    for (int kb = 0; kb < 4; ++kb) {
      s16x8 a = *(const s16x8*)(A2l + aoff2 + kb * 32);
#pragma unroll
      for (int nt = 0; nt < 4; ++nt) {
        s16x8 bf = *(const s16x8*)(W2l + (nt * 16 + m) * 136 + kb * 32 + q * 8);
        bacc[nt] = __builtin_amdgcn_mfma_f32_16x16x32_bf16(a, bf, bacc[nt], 0, 0, 0);
      }
    }
#pragma unroll
    for (int nt = 0; nt < 4; ++nt) {
      int ch = h2 * 64 + nt * 16 + m;
      float bb = b2[ch];
      float s = 0.f, sq = 0.f;
#pragma unroll
      for (int r4 = 0; r4 < 4; ++r4) {
        float y = bacc[nt][r4] + bb;
        s += y; sq += y * y;
        y2r[h2][nt][r4] = bacc[nt][r4];
      }
      s += __shfl_xor(s, 16); sq += __shfl_xor(sq, 16);
      s += __shfl_xor(s, 32); sq += __shfl_xor(sq, 32);
      if (q == 0) { sredS[ch * 8 + rw] = s; sredQ[ch * 8 + rw] = sq; }
    }
    __syncthreads();
    if (t < 64) {
      int ch = h2 * 64 + t;
      float ss = 0.f, qq = 0.f;
#pragma unroll
      for (int i2 = 0; i2 < 8; ++i2) { ss += sredS[ch * 8 + i2]; qq += sredQ[ch * 8 + i2]; }
      atomicAdd(&stats[256 + ch], ss);
      atomicAdd(&stats[384 + ch], qq);
    }
  }
  __syncthreads();
#pragma unroll
  for (int h2 = 0; h2 < 2; ++h2)
#pragma unroll
    for (int nt = 0; nt < 4; ++nt) {
      int ch = h2 * 64 + nt * 16 + m;
#pragma unroll
      for (int r4 = 0; r4 < 4; ++r4)
        A2l[(rw * 16 + q * 4 + r4) * 136 + ch] = f2bf(y2r[h2][nt][r4]);
    }
  __syncthreads();
  for (int i = t; i < 2048; i += 512) {
    int row = i >> 4, off = (i & 15) * 8;
    *(s16x8*)(Y2 + ((size_t)(T * 128 + row)) * 128 + off) = *(const s16x8*)(A2l + row * 136 + off);
  }
}

// ---------------- fin2 (unchanged from R8) ----------------
__global__ __launch_bounds__(512) void fin2_kernel(
    const unsigned short* __restrict__ Y2, const float* __restrict__ stats,
    const float* __restrict__ g2, const float* __restrict__ be2,
    const float* __restrict__ b2, const unsigned short* __restrict__ Wq1p_g,
    const float* __restrict__ bq1, const float* __restrict__ Wq2,
    const float* __restrict__ bq2, float* __restrict__ out_agg) {
  const int t = threadIdx.x;
  const int T = blockIdx.x;   // grid 4096, 64 rows each
  const int G0 = T * 2;
  const int b = G0 >> 11;

  __shared__ __align__(16) unsigned short Wq1l[8704];
  __shared__ float sc2a[128], sh2a[128];
  __shared__ float sv2[128], wv[64], agg2[512];

  const int lane = t & 63, wid = t >> 6;
  const int m = lane & 15, q = lane >> 4;
  const int rw = wid & 3, cw = wid >> 2;

  for (int i = t; i < 1088; i += 512) ((s16x8*)Wq1l)[i] = ((const s16x8*)Wq1p_g)[i];
  const float invN = 1.0f / 262144.0f;
  if (t < 128) {
    float mu2 = stats[256 + t] * invN;
    float var2 = stats[384 + t] * invN - mu2 * mu2;
    float s2 = g2[t] * rsqrtf(var2 + 1e-5f);
    sc2a[t] = s2;
    sh2a[t] = (b2[t] - mu2) * s2 + be2[t];
  }
  const int row = rw * 16 + m;
  const unsigned short* yr = Y2 + ((size_t)(T * 64 + row)) * 128;
  s16x8 yv[4];
#pragma unroll
  for (int kb = 0; kb < 4; ++kb) yv[kb] = *(const s16x8*)(yr + kb * 32 + q * 8);
  __syncthreads();  // b0

  float flr[4][8];
  s16x8 af[4];
#pragma unroll
  for (int kb = 0; kb < 4; ++kb) {
#pragma unroll
    for (int j = 0; j < 8; ++j) {
      int ch = kb * 32 + q * 8 + j;
      float f = fmaxf(bf2f((unsigned short)yv[kb][j]) * sc2a[ch] + sh2a[ch], 0.f);
      flr[kb][j] = f;
      af[kb][j] = (short)f2bf(f);
    }
  }
  {
    f32x4 qacc[2];
#pragma unroll
    for (int nt = 0; nt < 2; ++nt) qacc[nt] = (f32x4){0.f, 0.f, 0.f, 0.f};
#pragma unroll
    for (int kb = 0; kb < 4; ++kb) {
#pragma unroll
      for (int nt = 0; nt < 2; ++nt) {
        s16x8 bf = *(const s16x8*)(Wq1l + (cw * 32 + nt * 16 + m) * 136 + kb * 32 + q * 8);
        qacc[nt] = __builtin_amdgcn_mfma_f32_16x16x32_bf16(af[kb], bf, qacc[nt], 0, 0, 0);
      }
    }
    int qc0 = cw * 32 + m, qc1 = qc0 + 16;
    float ba0 = bq1[qc0], ba1 = bq1[qc1];
    float w0 = Wq2[qc0], w1 = Wq2[qc1];
    float part[4];
#pragma unroll
    for (int r4 = 0; r4 < 4; ++r4) {
      float v0 = fmaxf(qacc[0][r4] + ba0, 0.f);
      float v1 = fmaxf(qacc[1][r4] + ba1, 0.f);
      part[r4] = v0 * w0 + v1 * w1;
    }
#pragma unroll
    for (int d = 1; d < 16; d <<= 1) {
#pragma unroll
      for (int r4 = 0; r4 < 4; ++r4) part[r4] += __shfl_xor(part[r4], d);
    }
    if (m == 0) {
#pragma unroll
      for (int r4 = 0; r4 < 4; ++r4) sv2[(rw * 16 + q * 4 + r4) * 2 + cw] = part[r4];
    }
  }
  __syncthreads();  // b1
  if (t < 64) {
    float x = sv2[t * 2] + sv2[t * 2 + 1] + bq2[0];
    float mx = x;
#pragma unroll
    for (int d = 16; d; d >>= 1) mx = fmaxf(mx, __shfl_xor(mx, d, 32));
    float e = expf(x - mx);
    float ssum = e;
#pragma unroll
    for (int d = 16; d; d >>= 1) ssum += __shfl_xor(ssum, d, 32);
    wv[t] = e / ssum;
  }
  __syncthreads();  // b2
  if (cw == 0) {
    const float w = wv[row];
    const int gl = rw >> 1, rwpar = rw & 1;
#pragma unroll
    for (int kb = 0; kb < 4; ++kb) {
#pragma unroll
      for (int j = 0; j < 8; ++j) {
        float pv = w * flr[kb][j];
        pv += __shfl_xor(pv, 1);
        pv += __shfl_xor(pv, 2);
        pv += __shfl_xor(pv, 4);
        pv += __shfl_xor(pv, 8);
        if (m == 0) agg2[(gl * 128 + kb * 32 + q * 8 + j) * 2 + rwpar] = pv;
      }
    }
  }
  __syncthreads();  // b3
  if (t < 256) {
    int gl = t >> 7, ch = t & 127;
    float v = agg2[(gl * 128 + ch) * 2] + agg2[(gl * 128 + ch) * 2 + 1];
    out_agg[((size_t)(b * 128 + ch)) * 2048 + ((G0 + gl) & 2047)] = v;
  }
}

extern "C" void kernel_launch(void* const* d_in, const int* in_sizes, int n_in,
                              void* d_out, int out_size, void* d_ws, size_t ws_size,
                              hipStream_t stream) {
  const float* xyz   = (const float*)d_in[0];
  const float* feats = (const float*)d_in[1];
  const float* W1    = (const float*)d_in[2];
  const float* b1    = (const float*)d_in[3];
  const float* g1    = (const float*)d_in[4];
  const float* be1   = (const float*)d_in[5];
  const float* W2    = (const float*)d_in[6];
  const float* b2    = (const float*)d_in[7];
  const float* g2    = (const float*)d_in[8];
  const float* be2   = (const float*)d_in[9];
  const float* Wq1   = (const float*)d_in[10];
  const float* bq1   = (const float*)d_in[11];
  const float* Wq2   = (const float*)d_in[12];
  const float* bq2   = (const float*)d_in[13];

  float* outp    = (float*)d_out;
  float* centers = outp;           // (4,2048,3)
  float* out_agg = outp + 24576;   // (4,128,2048)

  // ws layout: 6.4 MB base; [8M,16M) cnt partials (pre-fwd) then Y2 [8M,72M)
  char* base = (char*)d_ws;
  unsigned short* featsT = (unsigned short*)base;                  // 4,194,304
  float4* xyzq  = (float4*)(base + 4194304);                       //   524,288
  int*    idxb  = (int*)(base + 4718592);                          // 1,048,576
  unsigned short* W1p  = (unsigned short*)(base + 5767168);        //    26,624
  unsigned short* W2p  = (unsigned short*)(base + 5793792);        //    34,816
  unsigned short* Wq1p = (unsigned short*)(base + 5828608);        //    17,408
  float* stats  = (float*)(base + 5846016);   // zero region start (4880 floats)
  float* dstats = stats + 512;
  float* Fbar   = stats + 528;
  float* Sfd    = stats + 592;
  float* Sff    = stats + 784;
  float* cntp   = stats + 4880;               // fully overwritten
  float* scx    = cntp + 32768;
  float* scy    = scx + 32768;
  float* scz    = scy + 32768;
  float* partials = (float*)(base + 8388608);              // 8 MB, dead before fwd
  unsigned short* Y2 = (unsigned short*)(base + 8388608);  // 67,108,864 B
  const bool bigws = ws_size >= (size_t)75497472;
  const bool midws = ws_size >= (size_t)16777216;

  hipMemsetAsync(stats, 0, 19520, stream);
  prep2_kernel<<<794, 256, 0, stream>>>(W1, W2, Wq1, xyz, feats, W1p, W2p, Wq1p, xyzq, featsT);
  sel3_kernel<<<dim3(128, 4), 512, 0, stream>>>(xyzq, centers, idxb);
  if (midws) {
    cntA_kernel<<<256, 1024, 0, stream>>>(xyzq, centers, idxb, partials, dstats);
    cntB_kernel<<<512, 256, 0, stream>>>(partials, cntp, scx, scy, scz);
  } else {
    cnt16_kernel<<<16, 1024, 0, stream>>>(xyzq, centers, idxb, cntp, scx, scy, scz, dstats);
  }
  gram_kernel<<<dim3(64, 4), 256, 0, stream>>>(feats, xyzq, cntp, scx, scy, scz, Sff, Sfd, Fbar);
  fin_kernel<<<1, 256, 0, stream>>>(W1, b1, Sff, Sfd, Fbar, dstats, stats);
  if (bigws) {
    fwd_kernel<<<2048, 512, 0, stream>>>(xyz, featsT, idxb, centers,
                                         W1p, b1, g1, be1, W2p, b2, stats, Y2);
    fin2_kernel<<<4096, 512, 0, stream>>>(Y2, stats, g2, be2, b2,
                                          Wq1p, bq1, Wq2, bq2, out_agg);
  } else {
    mlp_kernel<2><<<2048, 512, 0, stream>>>(xyz, featsT, idxb, centers,
                                            W1p, b1, g1, be1, W2p, b2, g2, be2,
                                            Wq1p, bq1, Wq2, bq2, stats, out_agg);
    mlp_kernel<3><<<2048, 512, 0, stream>>>(xyz, featsT, idxb, centers,
                                            W1p, b1, g1, be1, W2p, b2, g2, be2,
                                            Wq1p, bq1, Wq2, bq2, stats, out_agg);
  }
}